// Round 4
// baseline (143.770 us; speedup 1.0000x reference)
//
#include <hip/hip_runtime.h>
#include <math.h>

#define NN 8192
#define IN_F 128
#define OUT_F 64
#define JS 8                   // K-splits
#define KR (NN / JS)           // 1024 K per wave
#define NSTEP (KR / 32)        // 32 MFMA K-steps per wave
#define PS_PART 65             // partial row stride (f32)
#define NSTR (16 * NN)         // Pt stride between N-frag groups (bf16 elems)

typedef __bf16 bf16x8 __attribute__((ext_vector_type(8)));
typedef float f32x4 __attribute__((ext_vector_type(4)));

// ---------------- K1: per node, Wh (64), s2 = lrelu(Wh).b[64:], E = exp(s2).
// Writes Pt DIRECTLY (transposed): Pt[f][row] = bf16(E*Wh), Pt[64][row] = bf16(E).
// One wave per 4 rows; lane = output feature f.
__global__ __launch_bounds__(64) void k1_prep(const float* __restrict__ x,
                                              const float* __restrict__ W,
                                              const float* __restrict__ b,
                                              __bf16* __restrict__ Pt) {
    const int m0 = blockIdx.x * 4;
    const int f = threadIdx.x;                       // 0..63
    const float4* x4 = (const float4*)(x + (size_t)m0 * IN_F);
    float wh0 = 0.f, wh1 = 0.f, wh2 = 0.f, wh3 = 0.f;
    #pragma unroll
    for (int k4 = 0; k4 < IN_F / 4; ++k4) {
        const float w0 = W[(k4 * 4 + 0) * OUT_F + f];   // 256B coalesced, L2-hit
        const float w1 = W[(k4 * 4 + 1) * OUT_F + f];
        const float w2 = W[(k4 * 4 + 2) * OUT_F + f];
        const float w3 = W[(k4 * 4 + 3) * OUT_F + f];
        const float4 a0 = x4[k4];
        const float4 a1 = x4[32 + k4];
        const float4 a2 = x4[64 + k4];
        const float4 a3 = x4[96 + k4];
        wh0 = fmaf(a0.x, w0, fmaf(a0.y, w1, fmaf(a0.z, w2, fmaf(a0.w, w3, wh0))));
        wh1 = fmaf(a1.x, w0, fmaf(a1.y, w1, fmaf(a1.z, w2, fmaf(a1.w, w3, wh1))));
        wh2 = fmaf(a2.x, w0, fmaf(a2.y, w1, fmaf(a2.z, w2, fmaf(a2.w, w3, wh2))));
        wh3 = fmaf(a3.x, w0, fmaf(a3.y, w1, fmaf(a3.z, w2, fmaf(a3.w, w3, wh3))));
    }
    const float bb = b[OUT_F + f];
    float v0 = (wh0 >= 0.f ? wh0 : 0.2f * wh0) * bb;
    float v1 = (wh1 >= 0.f ? wh1 : 0.2f * wh1) * bb;
    float v2 = (wh2 >= 0.f ? wh2 : 0.2f * wh2) * bb;
    float v3 = (wh3 >= 0.f ? wh3 : 0.2f * wh3) * bb;
    #pragma unroll
    for (int off = 32; off; off >>= 1) {
        v0 += __shfl_xor(v0, off, 64);
        v1 += __shfl_xor(v1, off, 64);
        v2 += __shfl_xor(v2, off, 64);
        v3 += __shfl_xor(v3, off, 64);
    }
    const float E0 = expf(v0), E1 = expf(v1), E2 = expf(v2), E3 = expf(v3);
    Pt[(size_t)f * NN + m0 + 0] = (__bf16)(E0 * wh0);
    Pt[(size_t)f * NN + m0 + 1] = (__bf16)(E1 * wh1);
    Pt[(size_t)f * NN + m0 + 2] = (__bf16)(E2 * wh2);
    Pt[(size_t)f * NN + m0 + 3] = (__bf16)(E3 * wh3);
    if (f == 0) {
        Pt[(size_t)64 * NN + m0 + 0] = (__bf16)E0;
        Pt[(size_t)64 * NN + m0 + 1] = (__bf16)E1;
        Pt[(size_t)64 * NN + m0 + 2] = (__bf16)E2;
        Pt[(size_t)64 * NN + m0 + 3] = (__bf16)E3;
    }
}

// ---------------- K2: LDS-free, barrier-free streaming masked GEMM.
// wave wid: split s = wid>>9, row-group mg = wid&511 -> rows m0..m0+15, K-range s*1024.
__device__ __forceinline__ unsigned pk2(int a, int b) {
    return (a ? 0x3F80u : 0u) | (b ? 0x3F800000u : 0u);
}

#define LD_STEP(ks, A0, A1, B0, B1, B2, B3, B4)                 \
    A0 = ap[(ks) * 8];                                          \
    A1 = ap[(ks) * 8 + 1];                                      \
    B0 = *(const bf16x8*)(bp + (ks) * 32);                      \
    B1 = *(const bf16x8*)(bp + NSTR + (ks) * 32);               \
    B2 = *(const bf16x8*)(bp + 2 * NSTR + (ks) * 32);           \
    B3 = *(const bf16x8*)(bp + 3 * NSTR + (ks) * 32);           \
    B4 = *(const bf16x8*)(bp + 4 * NSTR + (ks) * 32);

#define DO_STEP(A0, A1, B0, B1, B2, B3, B4)                                        \
    {                                                                              \
        union { uint4 u; bf16x8 h; } _c;                                           \
        _c.u = make_uint4(pk2(A0.x, A0.y), pk2(A0.z, A0.w),                        \
                          pk2(A1.x, A1.y), pk2(A1.z, A1.w));                       \
        acc0 = __builtin_amdgcn_mfma_f32_16x16x32_bf16(_c.h, B0, acc0, 0, 0, 0);   \
        acc1 = __builtin_amdgcn_mfma_f32_16x16x32_bf16(_c.h, B1, acc1, 0, 0, 0);   \
        acc2 = __builtin_amdgcn_mfma_f32_16x16x32_bf16(_c.h, B2, acc2, 0, 0, 0);   \
        acc3 = __builtin_amdgcn_mfma_f32_16x16x32_bf16(_c.h, B3, acc3, 0, 0, 0);   \
        acc4 = __builtin_amdgcn_mfma_f32_16x16x32_bf16(_c.h, B4, acc4, 0, 0, 0);   \
    }

__global__ __launch_bounds__(256) void k2_stream(const int* __restrict__ adj,
                                                 const __bf16* __restrict__ Pt,
                                                 float* __restrict__ part) {
    const int wid = (blockIdx.x << 2) + (threadIdx.x >> 6);   // 0..4095
    const int l = threadIdx.x & 63;
    const int s = wid >> 9;                 // split 0..7 (block's 4 waves share s)
    const int m0 = (wid & 511) << 4;        // row-group base
    const int kbase = s * KR;
    const int lm = l & 15;
    const int lk8 = (l >> 4) << 3;          // 0,8,16,24 (elems)

    const int4* ap = (const int4*)(adj + (size_t)(m0 + lm) * NN + kbase + lk8);
    const __bf16* bp = Pt + (size_t)lm * NN + kbase + lk8;

    f32x4 acc0{}, acc1{}, acc2{}, acc3{}, acc4{};

    int4 xA0, xA1, xB0, xB1;
    bf16x8 yA0, yA1, yA2, yA3, yA4, yB0, yB1, yB2, yB3, yB4;

    LD_STEP(0, xA0, xA1, yA0, yA1, yA2, yA3, yA4)
    #pragma unroll
    for (int ks = 0; ks < NSTEP; ks += 2) {
        LD_STEP(ks + 1, xB0, xB1, yB0, yB1, yB2, yB3, yB4)
        DO_STEP(xA0, xA1, yA0, yA1, yA2, yA3, yA4)
        if (ks + 2 < NSTEP) {
            LD_STEP(ks + 2, xA0, xA1, yA0, yA1, yA2, yA3, yA4)
        }
        DO_STEP(xB0, xB1, yB0, yB1, yB2, yB3, yB4)
    }

    // epilogue: C/D layout col = lane&15, row = (lane>>4)*4 + reg
    float* pb = part + ((size_t)s * NN + m0 + ((l >> 4) << 2)) * PS_PART + lm;
    #pragma unroll
    for (int r = 0; r < 4; ++r) {
        pb[r * PS_PART]      = acc0[r];
        pb[r * PS_PART + 16] = acc1[r];
        pb[r * PS_PART + 32] = acc2[r];
        pb[r * PS_PART + 48] = acc3[r];
        if (lm == 0) pb[r * PS_PART + 64] = acc4[r];
    }
}

// ---------------- K3: combine splits, out = elu(num/den)
__global__ __launch_bounds__(256) void k3_combine(const float* __restrict__ part,
                                                  float* __restrict__ out) {
    const int idx = blockIdx.x * 256 + threadIdx.x;
    const int i = idx >> 6;
    const int f = idx & 63;
    float num = 0.f, den = 0.f;
    #pragma unroll
    for (int s = 0; s < JS; ++s) {
        num += part[((size_t)s * NN + i) * PS_PART + f];
        den += part[((size_t)s * NN + i) * PS_PART + 64];
    }
    const float o = num / den;
    out[idx] = o > 0.f ? o : expm1f(o);
}

extern "C" void kernel_launch(void* const* d_in, const int* in_sizes, int n_in,
                              void* d_out, int out_size, void* d_ws, size_t ws_size,
                              hipStream_t stream) {
    const float* x   = (const float*)d_in[0];   // [8192,128]
    const int*   adj = (const int*)d_in[1];     // [8192,8192]
    const float* W   = (const float*)d_in[2];   // [128,64]
    const float* b   = (const float*)d_in[3];   // [128]
    float* out = (float*)d_out;

    __bf16* Pt  = (__bf16*)d_ws;                       // 80*8192*2  = 1.31 MB
    float* part = (float*)((char*)d_ws + (size_t)80 * NN * sizeof(__bf16));
                                                       // 8*8192*65*4 = 17.04 MB

    k1_prep<<<NN / 4, 64, 0, stream>>>(x, W, b, Pt);
    k2_stream<<<(JS * NN / 16) / 4, 256, 0, stream>>>(adj, Pt, part);
    k3_combine<<<(NN * OUT_F) / 256, 256, 0, stream>>>(part, out);
}

// Round 7
// 143.698 us; speedup vs baseline: 1.0005x; 1.0005x over previous
//
#include <hip/hip_runtime.h>
#include <math.h>

#define NN 8192
#define IN_F 128
#define OUT_F 64
#define JS 4                    // K-splits
#define KR (NN / JS)            // 2048 K per wave
#define NPAIR 32                // 64 K-steps of 32 = 32 step-pairs
#define PS_PART 65              // partial row stride (f32)
#define NSTR (16 * NN)          // Pt stride between 16-row N-frag groups

typedef __bf16 bf16x8 __attribute__((ext_vector_type(8)));
typedef float f32x4 __attribute__((ext_vector_type(4)));
typedef unsigned long long u64;

// ---------------- K0: compress adj (int32 0/1, 256MB) -> bitmask (8MB).
// bits[row*128 + k/64] bit (k&63) = adj[row][k] != 0.
// 32768 waves x 8 segments; per segment: 4 x 256B contiguous loads + 4 ballots + 32B store.
__global__ __launch_bounds__(256) void k0_bits(const int* __restrict__ adj,
                                               u64* __restrict__ bits) {
    const int w = (blockIdx.x << 2) + (threadIdx.x >> 6);   // 0..32767
    const int l = threadIdx.x & 63;
    #pragma unroll
    for (int it = 0; it < 8; ++it) {
        const int g = (w << 3) + it;                        // 0..262143 (all segments)
        const int* p = adj + ((size_t)g << 8) + l;
        const u64 b0 = __ballot(p[0]   != 0);
        const u64 b1 = __ballot(p[64]  != 0);
        const u64 b2 = __ballot(p[128] != 0);
        const u64 b3 = __ballot(p[192] != 0);
        if (l == 0) {
            u64* q = bits + ((size_t)g << 2);
            q[0] = b0; q[1] = b1; q[2] = b2; q[3] = b3;
        }
    }
}

// ---------------- K1: per node, Wh (64), s2 = lrelu(Wh).b[64:], E = exp(s2).
// Writes Pt transposed: Pt[f][row] = bf16(E*Wh_f), Pt[64][row] = bf16(E), rows 65..79 = 0.
__global__ __launch_bounds__(64) void k1_prep(const float* __restrict__ x,
                                              const float* __restrict__ W,
                                              const float* __restrict__ b,
                                              __bf16* __restrict__ Pt) {
    const int m0 = blockIdx.x * 4;
    const int f = threadIdx.x;
    const float4* x4 = (const float4*)(x + (size_t)m0 * IN_F);
    float wh0 = 0.f, wh1 = 0.f, wh2 = 0.f, wh3 = 0.f;
    #pragma unroll
    for (int k4 = 0; k4 < IN_F / 4; ++k4) {
        const float w0 = W[(k4 * 4 + 0) * OUT_F + f];
        const float w1 = W[(k4 * 4 + 1) * OUT_F + f];
        const float w2 = W[(k4 * 4 + 2) * OUT_F + f];
        const float w3 = W[(k4 * 4 + 3) * OUT_F + f];
        const float4 a0 = x4[k4];
        const float4 a1 = x4[32 + k4];
        const float4 a2 = x4[64 + k4];
        const float4 a3 = x4[96 + k4];
        wh0 = fmaf(a0.x, w0, fmaf(a0.y, w1, fmaf(a0.z, w2, fmaf(a0.w, w3, wh0))));
        wh1 = fmaf(a1.x, w0, fmaf(a1.y, w1, fmaf(a1.z, w2, fmaf(a1.w, w3, wh1))));
        wh2 = fmaf(a2.x, w0, fmaf(a2.y, w1, fmaf(a2.z, w2, fmaf(a2.w, w3, wh2))));
        wh3 = fmaf(a3.x, w0, fmaf(a3.y, w1, fmaf(a3.z, w2, fmaf(a3.w, w3, wh3))));
    }
    const float bb = b[OUT_F + f];
    float v0 = (wh0 >= 0.f ? wh0 : 0.2f * wh0) * bb;
    float v1 = (wh1 >= 0.f ? wh1 : 0.2f * wh1) * bb;
    float v2 = (wh2 >= 0.f ? wh2 : 0.2f * wh2) * bb;
    float v3 = (wh3 >= 0.f ? wh3 : 0.2f * wh3) * bb;
    #pragma unroll
    for (int off = 32; off; off >>= 1) {
        v0 += __shfl_xor(v0, off, 64);
        v1 += __shfl_xor(v1, off, 64);
        v2 += __shfl_xor(v2, off, 64);
        v3 += __shfl_xor(v3, off, 64);
    }
    const float E0 = expf(v0), E1 = expf(v1), E2 = expf(v2), E3 = expf(v3);
    Pt[(size_t)f * NN + m0 + 0] = (__bf16)(E0 * wh0);
    Pt[(size_t)f * NN + m0 + 1] = (__bf16)(E1 * wh1);
    Pt[(size_t)f * NN + m0 + 2] = (__bf16)(E2 * wh2);
    Pt[(size_t)f * NN + m0 + 3] = (__bf16)(E3 * wh3);
    if (f == 0) {
        Pt[(size_t)64 * NN + m0 + 0] = (__bf16)E0;
        Pt[(size_t)64 * NN + m0 + 1] = (__bf16)E1;
        Pt[(size_t)64 * NN + m0 + 2] = (__bf16)E2;
        Pt[(size_t)64 * NN + m0 + 3] = (__bf16)E3;
    }
    // zero pad rows 65..79 (4 cols per block, 60 threads): independence from ws poison
    if (f < 60) {
        const int r = 65 + (f >> 2);
        const int c = f & 3;
        Pt[(size_t)r * NN + m0 + c] = (__bf16)0.f;
    }
}

// unpack 8 mask bits -> bf16x8 of {0.0, 1.0}
__device__ __forceinline__ bf16x8 unp8(u64 w, int sh) {
    const unsigned b = (unsigned)(w >> sh) & 0xFFu;
    union { unsigned u[4]; bf16x8 h; } c;
    c.u[0] = ((b)      & 1u) * 0x3F80u | ((b >> 1) & 1u) * 0x3F800000u;
    c.u[1] = ((b >> 2) & 1u) * 0x3F80u | ((b >> 3) & 1u) * 0x3F800000u;
    c.u[2] = ((b >> 4) & 1u) * 0x3F80u | ((b >> 5) & 1u) * 0x3F800000u;
    c.u[3] = ((b >> 6) & 1u) * 0x3F80u | ((b >> 7) & 1u) * 0x3F800000u;
    return c.h;
}

#define MFMA5(f, B0, B1, B2, B3, B4)                                      \
    a0 = __builtin_amdgcn_mfma_f32_16x16x32_bf16(f, B0, a0, 0, 0, 0);     \
    a1 = __builtin_amdgcn_mfma_f32_16x16x32_bf16(f, B1, a1, 0, 0, 0);     \
    a2 = __builtin_amdgcn_mfma_f32_16x16x32_bf16(f, B2, a2, 0, 0, 0);     \
    a3 = __builtin_amdgcn_mfma_f32_16x16x32_bf16(f, B3, a3, 0, 0, 0);     \
    a4 = __builtin_amdgcn_mfma_f32_16x16x32_bf16(f, B4, a4, 0, 0, 0);

// ---------------- K2: bitmask MFMA GEMM. Wave: 16 rows x 80 cols x K-range 2048.
// 2048 waves (512 blocks x 4, 8 waves/CU). A from bitmask (L3), B from Pt (L2).
__global__ __launch_bounds__(256, 2) void k2_bits(const u64* __restrict__ bits,
                                                  const __bf16* __restrict__ Pt,
                                                  float* __restrict__ part) {
    const int wid = (blockIdx.x << 2) + (threadIdx.x >> 6);   // 0..2047
    const int l = threadIdx.x & 63;
    const int s = wid >> 9;                 // split 0..3 (block-uniform)
    const int m0 = (wid & 511) << 4;        // 16-row group base
    const int kbase = s * KR;
    const int lm = l & 15, lg = l >> 4;
    const int sh0 = lg << 3;                // byte sel, even K-step
    const int sh1 = 32 + (lg << 3);         // byte sel, odd K-step

    const u64* bp0 = bits + (size_t)(m0 + lm) * (NN / 64) + (kbase >> 6);
    const __bf16* pt0 = Pt + (size_t)lm * NN + kbase + (lg << 3);
    const __bf16* pt1 = pt0 + NSTR;
    const __bf16* pt2 = pt0 + 2 * NSTR;
    const __bf16* pt3 = pt0 + 3 * NSTR;
    const __bf16* pt4 = pt0 + (size_t)4 * NSTR;

    f32x4 a0{}, a1{}, a2{}, a3{}, a4{};

    u64 wA = bp0[0];

    #pragma unroll
    for (int p = 0; p < NPAIR; ++p) {
        const int o0 = p * 64;              // even step elem offset (2p)*32
        const int o1 = o0 + 32;
        const bf16x8 B00 = *(const bf16x8*)(pt0 + o0);
        const bf16x8 B01 = *(const bf16x8*)(pt1 + o0);
        const bf16x8 B02 = *(const bf16x8*)(pt2 + o0);
        const bf16x8 B03 = *(const bf16x8*)(pt3 + o0);
        const bf16x8 B04 = *(const bf16x8*)(pt4 + o0);
        const bf16x8 B10 = *(const bf16x8*)(pt0 + o1);
        const bf16x8 B11 = *(const bf16x8*)(pt1 + o1);
        const bf16x8 B12 = *(const bf16x8*)(pt2 + o1);
        const bf16x8 B13 = *(const bf16x8*)(pt3 + o1);
        const bf16x8 B14 = *(const bf16x8*)(pt4 + o1);
        u64 nA = 0;
        if (p + 1 < NPAIR) nA = bp0[p + 1];
        bf16x8 f0 = unp8(wA, sh0);
        MFMA5(f0, B00, B01, B02, B03, B04)
        f0 = unp8(wA, sh1);
        MFMA5(f0, B10, B11, B12, B13, B14)
        wA = nA;
    }

    // epilogue: C/D col = lane&15, row = lg*4 + reg
    float* pb = part + ((size_t)s * NN + m0 + (lg << 2)) * PS_PART + lm;
    #pragma unroll
    for (int r = 0; r < 4; ++r) {
        pb[r * PS_PART]      = a0[r];
        pb[r * PS_PART + 16] = a1[r];
        pb[r * PS_PART + 32] = a2[r];
        pb[r * PS_PART + 48] = a3[r];
        if (lm == 0) pb[r * PS_PART + 64] = a4[r];
    }
}

// ---------------- K3: combine splits, out = elu(num/den)
__global__ __launch_bounds__(256) void k3_combine(const float* __restrict__ part,
                                                  float* __restrict__ out) {
    const int idx = blockIdx.x * 256 + threadIdx.x;
    const int i = idx >> 6;
    const int f = idx & 63;
    float num = 0.f, den = 0.f;
    #pragma unroll
    for (int s = 0; s < JS; ++s) {
        num += part[((size_t)s * NN + i) * PS_PART + f];
        den += part[((size_t)s * NN + i) * PS_PART + 64];
    }
    const float o = num / den;
    out[idx] = o > 0.f ? o : expm1f(o);
}

extern "C" void kernel_launch(void* const* d_in, const int* in_sizes, int n_in,
                              void* d_out, int out_size, void* d_ws, size_t ws_size,
                              hipStream_t stream) {
    const float* x   = (const float*)d_in[0];   // [8192,128]
    const int*   adj = (const int*)d_in[1];     // [8192,8192]
    const float* W   = (const float*)d_in[2];   // [128,64]
    const float* b   = (const float*)d_in[3];   // [128]
    float* out = (float*)d_out;

    u64*    bits = (u64*)d_ws;                                  // 8192*128*8 = 8.39 MB
    __bf16* Pt   = (__bf16*)(bits + (size_t)NN * (NN / 64));    // 80*8192*2  = 1.31 MB
    float*  part = (float*)(Pt + (size_t)80 * NN);              // 4*8192*65*4 = 8.52 MB

    k0_bits<<<8192, 256, 0, stream>>>(adj, bits);
    k1_prep<<<NN / 4, 64, 0, stream>>>(x, W, b, Pt);
    k2_bits<<<512, 256, 0, stream>>>(bits, Pt, part);
    k3_combine<<<(NN * OUT_F) / 256, 256, 0, stream>>>(part, out);
}

// Round 8
// 120.645 us; speedup vs baseline: 1.1917x; 1.1911x over previous
//
#include <hip/hip_runtime.h>
#include <math.h>

#define NN 8192
#define IN_F 128
#define OUT_F 64
#define JS 8                    // K-splits
#define KR (NN / JS)            // 1024 K per block
#define BK 128                  // K per tile
#define TILES (KR / BK)         // 8
#define PS_PART 65              // partial row stride (f32)
#define LP 130                  // LDS Pt pitch (bf16): bank = (lm + 4*lg) % 32, <=2-way

typedef __bf16 bf16x8 __attribute__((ext_vector_type(8)));
typedef float f32x4 __attribute__((ext_vector_type(4)));
typedef unsigned long long u64;

// ---------------- K0: compress adj (int32 0/1, 256MB) -> bitmask (8MB).
__global__ __launch_bounds__(256) void k0_bits(const int* __restrict__ adj,
                                               u64* __restrict__ bits) {
    const int w = (blockIdx.x << 2) + (threadIdx.x >> 6);   // 0..32767
    const int l = threadIdx.x & 63;
    #pragma unroll
    for (int it = 0; it < 8; ++it) {
        const int g = (w << 3) + it;                        // all 262144 segments
        const int* p = adj + ((size_t)g << 8) + l;
        const u64 b0 = __ballot(p[0]   != 0);
        const u64 b1 = __ballot(p[64]  != 0);
        const u64 b2 = __ballot(p[128] != 0);
        const u64 b3 = __ballot(p[192] != 0);
        if (l < 4) {                                        // one 32B coalesced group
            const u64 v = l == 0 ? b0 : (l == 1 ? b1 : (l == 2 ? b2 : b3));
            bits[((size_t)g << 2) + l] = v;
        }
    }
}

// ---------------- K1: per node, Wh (64), s2 = lrelu(Wh).b[64:], E = exp(s2).
// Pt[f][row] = bf16(E*Wh_f), Pt[64][row] = bf16(E), rows 65..79 = 0.
__global__ __launch_bounds__(64) void k1_prep(const float* __restrict__ x,
                                              const float* __restrict__ W,
                                              const float* __restrict__ b,
                                              __bf16* __restrict__ Pt) {
    const int m0 = blockIdx.x * 4;
    const int f = threadIdx.x;
    const float4* x4 = (const float4*)(x + (size_t)m0 * IN_F);
    float wh0 = 0.f, wh1 = 0.f, wh2 = 0.f, wh3 = 0.f;
    #pragma unroll
    for (int k4 = 0; k4 < IN_F / 4; ++k4) {
        const float w0 = W[(k4 * 4 + 0) * OUT_F + f];
        const float w1 = W[(k4 * 4 + 1) * OUT_F + f];
        const float w2 = W[(k4 * 4 + 2) * OUT_F + f];
        const float w3 = W[(k4 * 4 + 3) * OUT_F + f];
        const float4 a0 = x4[k4];
        const float4 a1 = x4[32 + k4];
        const float4 a2 = x4[64 + k4];
        const float4 a3 = x4[96 + k4];
        wh0 = fmaf(a0.x, w0, fmaf(a0.y, w1, fmaf(a0.z, w2, fmaf(a0.w, w3, wh0))));
        wh1 = fmaf(a1.x, w0, fmaf(a1.y, w1, fmaf(a1.z, w2, fmaf(a1.w, w3, wh1))));
        wh2 = fmaf(a2.x, w0, fmaf(a2.y, w1, fmaf(a2.z, w2, fmaf(a2.w, w3, wh2))));
        wh3 = fmaf(a3.x, w0, fmaf(a3.y, w1, fmaf(a3.z, w2, fmaf(a3.w, w3, wh3))));
    }
    const float bb = b[OUT_F + f];
    float v0 = (wh0 >= 0.f ? wh0 : 0.2f * wh0) * bb;
    float v1 = (wh1 >= 0.f ? wh1 : 0.2f * wh1) * bb;
    float v2 = (wh2 >= 0.f ? wh2 : 0.2f * wh2) * bb;
    float v3 = (wh3 >= 0.f ? wh3 : 0.2f * wh3) * bb;
    #pragma unroll
    for (int off = 32; off; off >>= 1) {
        v0 += __shfl_xor(v0, off, 64);
        v1 += __shfl_xor(v1, off, 64);
        v2 += __shfl_xor(v2, off, 64);
        v3 += __shfl_xor(v3, off, 64);
    }
    const float E0 = expf(v0), E1 = expf(v1), E2 = expf(v2), E3 = expf(v3);
    Pt[(size_t)f * NN + m0 + 0] = (__bf16)(E0 * wh0);
    Pt[(size_t)f * NN + m0 + 1] = (__bf16)(E1 * wh1);
    Pt[(size_t)f * NN + m0 + 2] = (__bf16)(E2 * wh2);
    Pt[(size_t)f * NN + m0 + 3] = (__bf16)(E3 * wh3);
    if (f == 0) {
        Pt[(size_t)64 * NN + m0 + 0] = (__bf16)E0;
        Pt[(size_t)64 * NN + m0 + 1] = (__bf16)E1;
        Pt[(size_t)64 * NN + m0 + 2] = (__bf16)E2;
        Pt[(size_t)64 * NN + m0 + 3] = (__bf16)E3;
    }
    if (f < 60) {       // zero pad rows 65..79 for this block's 4 cols
        const int r = 65 + (f >> 2);
        const int c = f & 3;
        Pt[(size_t)r * NN + m0 + c] = (__bf16)0.f;
    }
}

// unpack 8 mask bits -> bf16x8 of {0.0, 1.0}
__device__ __forceinline__ bf16x8 unp8(u64 w, int sh) {
    const unsigned b = (unsigned)(w >> sh) & 0xFFu;
    union { unsigned u[4]; bf16x8 h; } c;
    c.u[0] = ((b)      & 1u) * 0x3F80u | ((b >> 1) & 1u) * 0x3F800000u;
    c.u[1] = ((b >> 2) & 1u) * 0x3F80u | ((b >> 3) & 1u) * 0x3F800000u;
    c.u[2] = ((b >> 4) & 1u) * 0x3F80u | ((b >> 5) & 1u) * 0x3F800000u;
    c.u[3] = ((b >> 6) & 1u) * 0x3F80u | ((b >> 7) & 1u) * 0x3F800000u;
    return c.h;
}

// ---------------- K2: bitmask MFMA GEMM, LDS-shared Pt.
// Block: 256 thr / 4 waves, 64 rows, K-range 1024 (split s). Wave w: rows m0+16w..+15.
__global__ __launch_bounds__(256, 3) void k2_bits(const u64* __restrict__ bits,
                                                  const __bf16* __restrict__ Pt,
                                                  float* __restrict__ part) {
    const int bid = blockIdx.x;             // 0..1023
    const int mblk = bid & 127;
    const int s = bid >> 7;
    const int tid = threadIdx.x;
    const int w = tid >> 6, l = tid & 63;
    const int lm = l & 15, lg = l >> 4;
    const int m0 = mblk << 6;
    const int kbase = s * KR;

    __shared__ __bf16 Ps[2][80][LP];        // 41600 B

    // Pt staging map: 1280 16B-chunks, 5 per thread
    int sr[5], sc[5];
    #pragma unroll
    for (int j = 0; j < 5; ++j) {
        const int q = tid + (j << 8);
        sr[j] = q >> 4;
        sc[j] = q & 15;
    }
    uint4 stg[5];
    #pragma unroll
    for (int j = 0; j < 5; ++j)
        stg[j] = *(const uint4*)(Pt + (size_t)sr[j] * NN + kbase + (sc[j] << 3));

    // A-bits: this wave's row, 2 u64 per tile
    const u64* bp = bits + (size_t)(m0 + (w << 4) + lm) * (NN / 64) + (kbase >> 6);
    u64 wa0 = bp[0], wa1 = bp[1];

    f32x4 a0{}, a1{}, a2{}, a3{}, a4{};
    const int sh = lg << 3;

    for (int t = 0; t < TILES; ++t) {
        const int buf = t & 1;
        #pragma unroll
        for (int j = 0; j < 5; ++j)
            *(uint4*)&Ps[buf][sr[j]][sc[j] << 3] = stg[j];
        __syncthreads();
        // issue next-tile loads now: they fly under the MFMA phase
        u64 na0 = 0, na1 = 0;
        if (t + 1 < TILES) {
            #pragma unroll
            for (int j = 0; j < 5; ++j)
                stg[j] = *(const uint4*)(Pt + (size_t)sr[j] * NN + kbase +
                                         (t + 1) * BK + (sc[j] << 3));
            na0 = bp[(t + 1) * 2];
            na1 = bp[(t + 1) * 2 + 1];
        }
        #pragma unroll
        for (int ks = 0; ks < 4; ++ks) {
            const int o = ks * 32 + sh;
            const bf16x8 B0 = *(const bf16x8*)&Ps[buf][lm][o];
            const bf16x8 B1 = *(const bf16x8*)&Ps[buf][16 + lm][o];
            const bf16x8 B2 = *(const bf16x8*)&Ps[buf][32 + lm][o];
            const bf16x8 B3 = *(const bf16x8*)&Ps[buf][48 + lm][o];
            const bf16x8 B4 = *(const bf16x8*)&Ps[buf][64 + lm][o];
            const u64 wv = (ks < 2) ? wa0 : wa1;
            const bf16x8 af = unp8(wv, ((ks & 1) << 5) + sh);
            a0 = __builtin_amdgcn_mfma_f32_16x16x32_bf16(af, B0, a0, 0, 0, 0);
            a1 = __builtin_amdgcn_mfma_f32_16x16x32_bf16(af, B1, a1, 0, 0, 0);
            a2 = __builtin_amdgcn_mfma_f32_16x16x32_bf16(af, B2, a2, 0, 0, 0);
            a3 = __builtin_amdgcn_mfma_f32_16x16x32_bf16(af, B3, a3, 0, 0, 0);
            a4 = __builtin_amdgcn_mfma_f32_16x16x32_bf16(af, B4, a4, 0, 0, 0);
        }
        wa0 = na0; wa1 = na1;
    }

    // epilogue: C/D col = lane&15, row = lg*4 + reg
    float* pb = part + ((size_t)s * NN + m0 + (w << 4) + (lg << 2)) * PS_PART + lm;
    #pragma unroll
    for (int r = 0; r < 4; ++r) {
        pb[r * PS_PART]      = a0[r];
        pb[r * PS_PART + 16] = a1[r];
        pb[r * PS_PART + 32] = a2[r];
        pb[r * PS_PART + 48] = a3[r];
        if (lm == 0) pb[r * PS_PART + 64] = a4[r];
    }
}

// ---------------- K3: combine splits, out = elu(num/den)
__global__ __launch_bounds__(256) void k3_combine(const float* __restrict__ part,
                                                  float* __restrict__ out) {
    const int idx = blockIdx.x * 256 + threadIdx.x;
    const int i = idx >> 6;
    const int f = idx & 63;
    float num = 0.f, den = 0.f;
    #pragma unroll
    for (int s = 0; s < JS; ++s) {
        num += part[((size_t)s * NN + i) * PS_PART + f];
        den += part[((size_t)s * NN + i) * PS_PART + 64];
    }
    const float o = num / den;
    out[idx] = o > 0.f ? o : expm1f(o);
}

extern "C" void kernel_launch(void* const* d_in, const int* in_sizes, int n_in,
                              void* d_out, int out_size, void* d_ws, size_t ws_size,
                              hipStream_t stream) {
    const float* x   = (const float*)d_in[0];   // [8192,128]
    const int*   adj = (const int*)d_in[1];     // [8192,8192]
    const float* W   = (const float*)d_in[2];   // [128,64]
    const float* b   = (const float*)d_in[3];   // [128]
    float* out = (float*)d_out;

    u64*    bits = (u64*)d_ws;                                  // 8.39 MB
    __bf16* Pt   = (__bf16*)(bits + (size_t)NN * (NN / 64));    // 1.31 MB
    float*  part = (float*)(Pt + (size_t)80 * NN);              // 8*8192*65*4 = 17.04 MB

    k0_bits<<<8192, 256, 0, stream>>>(adj, bits);
    k1_prep<<<NN / 4, 64, 0, stream>>>(x, W, b, Pt);
    k2_bits<<<1024, 256, 0, stream>>>(bits, Pt, part);
    k3_combine<<<(NN * OUT_F) / 256, 256, 0, stream>>>(part, out);
}

// Round 9
// 117.367 us; speedup vs baseline: 1.2250x; 1.0279x over previous
//
#include <hip/hip_runtime.h>
#include <math.h>

#define NN 8192
#define IN_F 128
#define OUT_F 64
#define JS 4                    // K-splits
#define KR (NN / JS)            // 2048 K per block
#define BK 128                  // K per tile
#define TILES (KR / BK)         // 16
#define PS_PART 65              // partial row stride (f32)
#define LP 136                  // LDS Pt pitch (bf16): 272B rows, 16B-aligned, <=2-way banks

typedef __bf16 bf16x8 __attribute__((ext_vector_type(8)));
typedef float f32x4 __attribute__((ext_vector_type(4)));
typedef unsigned long long u64;

// ---------------- K0: compress adj (int32 0/1, 256MB) -> bitmask (8MB).
// Wave covers 2048 consecutive ints (8KB). Per iter: lane loads int4 (1KB/instr
// contiguous), nibble = 4 compares, shfl_xor ladder packs 8 lanes -> u32.
__global__ __launch_bounds__(256) void k0_bits(const int* __restrict__ adj,
                                               unsigned* __restrict__ bitsw) {
    const int w = (blockIdx.x << 2) + (threadIdx.x >> 6);   // 0..32767
    const int l = threadIdx.x & 63;
    const int* base = adj + ((size_t)w << 11) + (l << 2);
    unsigned* ob = bitsw + (w << 6);                        // 64 u32 per wave
    #pragma unroll
    for (int it = 0; it < 8; ++it) {
        const int4 a = *(const int4*)(base + (it << 8));    // ints: w*2048+it*256+4l..+3
        unsigned v = (a.x != 0 ? 1u : 0u) | (a.y != 0 ? 2u : 0u) |
                     (a.z != 0 ? 4u : 0u) | (a.w != 0 ? 8u : 0u);
        v |= (unsigned)__shfl_xor((int)v, 1, 64) << 4;
        v |= (unsigned)__shfl_xor((int)v, 2, 64) << 8;
        v |= (unsigned)__shfl_xor((int)v, 4, 64) << 16;     // lanes 8k: ints 32*(it*8+k)
        if ((l & 7) == 0) ob[(it << 3) + (l >> 3)] = v;
    }
}

// ---------------- K1: per node, Wh (64), s2 = lrelu(Wh).b[64:], E = exp(s2).
// Pt[f][row] = bf16(E*Wh_f), Pt[64][row] = bf16(E), rows 65..79 = 0.
__global__ __launch_bounds__(64) void k1_prep(const float* __restrict__ x,
                                              const float* __restrict__ W,
                                              const float* __restrict__ b,
                                              __bf16* __restrict__ Pt) {
    const int m0 = blockIdx.x * 4;
    const int f = threadIdx.x;
    const float4* x4 = (const float4*)(x + (size_t)m0 * IN_F);
    float wh0 = 0.f, wh1 = 0.f, wh2 = 0.f, wh3 = 0.f;
    #pragma unroll
    for (int k4 = 0; k4 < IN_F / 4; ++k4) {
        const float w0 = W[(k4 * 4 + 0) * OUT_F + f];
        const float w1 = W[(k4 * 4 + 1) * OUT_F + f];
        const float w2 = W[(k4 * 4 + 2) * OUT_F + f];
        const float w3 = W[(k4 * 4 + 3) * OUT_F + f];
        const float4 a0 = x4[k4];
        const float4 a1 = x4[32 + k4];
        const float4 a2 = x4[64 + k4];
        const float4 a3 = x4[96 + k4];
        wh0 = fmaf(a0.x, w0, fmaf(a0.y, w1, fmaf(a0.z, w2, fmaf(a0.w, w3, wh0))));
        wh1 = fmaf(a1.x, w0, fmaf(a1.y, w1, fmaf(a1.z, w2, fmaf(a1.w, w3, wh1))));
        wh2 = fmaf(a2.x, w0, fmaf(a2.y, w1, fmaf(a2.z, w2, fmaf(a2.w, w3, wh2))));
        wh3 = fmaf(a3.x, w0, fmaf(a3.y, w1, fmaf(a3.z, w2, fmaf(a3.w, w3, wh3))));
    }
    const float bb = b[OUT_F + f];
    float v0 = (wh0 >= 0.f ? wh0 : 0.2f * wh0) * bb;
    float v1 = (wh1 >= 0.f ? wh1 : 0.2f * wh1) * bb;
    float v2 = (wh2 >= 0.f ? wh2 : 0.2f * wh2) * bb;
    float v3 = (wh3 >= 0.f ? wh3 : 0.2f * wh3) * bb;
    #pragma unroll
    for (int off = 32; off; off >>= 1) {
        v0 += __shfl_xor(v0, off, 64);
        v1 += __shfl_xor(v1, off, 64);
        v2 += __shfl_xor(v2, off, 64);
        v3 += __shfl_xor(v3, off, 64);
    }
    const float E0 = expf(v0), E1 = expf(v1), E2 = expf(v2), E3 = expf(v3);
    Pt[(size_t)f * NN + m0 + 0] = (__bf16)(E0 * wh0);
    Pt[(size_t)f * NN + m0 + 1] = (__bf16)(E1 * wh1);
    Pt[(size_t)f * NN + m0 + 2] = (__bf16)(E2 * wh2);
    Pt[(size_t)f * NN + m0 + 3] = (__bf16)(E3 * wh3);
    if (f == 0) {
        Pt[(size_t)64 * NN + m0 + 0] = (__bf16)E0;
        Pt[(size_t)64 * NN + m0 + 1] = (__bf16)E1;
        Pt[(size_t)64 * NN + m0 + 2] = (__bf16)E2;
        Pt[(size_t)64 * NN + m0 + 3] = (__bf16)E3;
    }
    if (f < 60) {       // zero pad rows 65..79 for this block's 4 cols
        const int r = 65 + (f >> 2);
        const int c = f & 3;
        Pt[(size_t)r * NN + m0 + c] = (__bf16)0.f;
    }
}

// unpack 8 mask bits -> bf16x8 of {0.0, 1.0}
__device__ __forceinline__ bf16x8 unp8(u64 w, int sh) {
    const unsigned b = (unsigned)(w >> sh) & 0xFFu;
    union { unsigned u[4]; bf16x8 h; } c;
    c.u[0] = ((b)      & 1u) * 0x3F80u | ((b >> 1) & 1u) * 0x3F800000u;
    c.u[1] = ((b >> 2) & 1u) * 0x3F80u | ((b >> 3) & 1u) * 0x3F800000u;
    c.u[2] = ((b >> 4) & 1u) * 0x3F80u | ((b >> 5) & 1u) * 0x3F800000u;
    c.u[3] = ((b >> 6) & 1u) * 0x3F80u | ((b >> 7) & 1u) * 0x3F800000u;
    return c.h;
}

// ---------------- K2: bitmask MFMA GEMM, LDS-shared Pt, double-buffered.
// Block: 256 thr / 4 waves, 64 rows, K-range 2048 (split s). Wave w: rows m0+16w..+15.
__global__ __launch_bounds__(256, 2) void k2_bits(const u64* __restrict__ bits,
                                                  const __bf16* __restrict__ Pt,
                                                  float* __restrict__ part) {
    const int bid = blockIdx.x;             // 0..511
    const int mblk = bid & 127;
    const int s = bid >> 7;
    const int tid = threadIdx.x;
    const int w = tid >> 6, l = tid & 63;
    const int lm = l & 15, lg = l >> 4;
    const int m0 = mblk << 6;
    const int kbase = s * KR;

    __shared__ __bf16 Ps[2][80][LP];        // 43,520 B

    // Pt staging map: 1280 16B-chunks, 5 per thread
    int sr[5], sc[5];
    #pragma unroll
    for (int j = 0; j < 5; ++j) {
        const int q = tid + (j << 8);
        sr[j] = q >> 4;
        sc[j] = q & 15;
    }
    uint4 stg[5];
    #pragma unroll
    for (int j = 0; j < 5; ++j)
        stg[j] = *(const uint4*)(Pt + (size_t)sr[j] * NN + kbase + (sc[j] << 3));

    // A-bits: this wave's row, 2 u64 per tile
    const u64* bp = bits + (size_t)(m0 + (w << 4) + lm) * (NN / 64) + (kbase >> 6);
    u64 wa0 = bp[0], wa1 = bp[1];

    f32x4 a0{}, a1{}, a2{}, a3{}, a4{};
    const int sh = lg << 3;

    for (int t = 0; t < TILES; ++t) {
        const int buf = t & 1;
        #pragma unroll
        for (int j = 0; j < 5; ++j)
            *(uint4*)&Ps[buf][sr[j]][sc[j] << 3] = stg[j];
        __syncthreads();
        // issue next-tile loads now: they fly under the MFMA phase
        u64 na0 = 0, na1 = 0;
        if (t + 1 < TILES) {
            #pragma unroll
            for (int j = 0; j < 5; ++j)
                stg[j] = *(const uint4*)(Pt + (size_t)sr[j] * NN + kbase +
                                         (t + 1) * BK + (sc[j] << 3));
            na0 = bp[(t + 1) * 2];
            na1 = bp[(t + 1) * 2 + 1];
        }
        #pragma unroll
        for (int ks = 0; ks < 4; ++ks) {
            const int o = ks * 32 + sh;
            const bf16x8 B0 = *(const bf16x8*)&Ps[buf][lm][o];
            const bf16x8 B1 = *(const bf16x8*)&Ps[buf][16 + lm][o];
            const bf16x8 B2 = *(const bf16x8*)&Ps[buf][32 + lm][o];
            const bf16x8 B3 = *(const bf16x8*)&Ps[buf][48 + lm][o];
            const bf16x8 B4 = *(const bf16x8*)&Ps[buf][64 + lm][o];
            const u64 wv = (ks < 2) ? wa0 : wa1;
            const bf16x8 af = unp8(wv, ((ks & 1) << 5) + sh);
            a0 = __builtin_amdgcn_mfma_f32_16x16x32_bf16(af, B0, a0, 0, 0, 0);
            a1 = __builtin_amdgcn_mfma_f32_16x16x32_bf16(af, B1, a1, 0, 0, 0);
            a2 = __builtin_amdgcn_mfma_f32_16x16x32_bf16(af, B2, a2, 0, 0, 0);
            a3 = __builtin_amdgcn_mfma_f32_16x16x32_bf16(af, B3, a3, 0, 0, 0);
            a4 = __builtin_amdgcn_mfma_f32_16x16x32_bf16(af, B4, a4, 0, 0, 0);
        }
        wa0 = na0; wa1 = na1;
    }

    // epilogue: C/D col = lane&15, row = lg*4 + reg
    float* pb = part + ((size_t)s * NN + m0 + (w << 4) + (lg << 2)) * PS_PART + lm;
    #pragma unroll
    for (int r = 0; r < 4; ++r) {
        pb[r * PS_PART]      = a0[r];
        pb[r * PS_PART + 16] = a1[r];
        pb[r * PS_PART + 32] = a2[r];
        pb[r * PS_PART + 48] = a3[r];
        if (lm == 0) pb[r * PS_PART + 64] = a4[r];
    }
}

// ---------------- K3: combine splits, out = elu(num/den)
__global__ __launch_bounds__(256) void k3_combine(const float* __restrict__ part,
                                                  float* __restrict__ out) {
    const int idx = blockIdx.x * 256 + threadIdx.x;
    const int i = idx >> 6;
    const int f = idx & 63;
    float num = 0.f, den = 0.f;
    #pragma unroll
    for (int s = 0; s < JS; ++s) {
        num += part[((size_t)s * NN + i) * PS_PART + f];
        den += part[((size_t)s * NN + i) * PS_PART + 64];
    }
    const float o = num / den;
    out[idx] = o > 0.f ? o : expm1f(o);
}

extern "C" void kernel_launch(void* const* d_in, const int* in_sizes, int n_in,
                              void* d_out, int out_size, void* d_ws, size_t ws_size,
                              hipStream_t stream) {
    const float* x   = (const float*)d_in[0];   // [8192,128]
    const int*   adj = (const int*)d_in[1];     // [8192,8192]
    const float* W   = (const float*)d_in[2];   // [128,64]
    const float* b   = (const float*)d_in[3];   // [128]
    float* out = (float*)d_out;

    u64*    bits = (u64*)d_ws;                                  // 8.39 MB
    __bf16* Pt   = (__bf16*)(bits + (size_t)NN * (NN / 64));    // 1.31 MB
    float*  part = (float*)(Pt + (size_t)80 * NN);              // 4*8192*65*4 = 8.52 MB

    k0_bits<<<8192, 256, 0, stream>>>(adj, (unsigned*)bits);
    k1_prep<<<NN / 4, 64, 0, stream>>>(x, W, b, Pt);
    k2_bits<<<512, 256, 0, stream>>>(bits, Pt, part);
    k3_combine<<<(NN * OUT_F) / 256, 256, 0, stream>>>(part, out);
}